// Round 2
// baseline (290.101 us; speedup 1.0000x reference)
//
#include <hip/hip_runtime.h>
#include <stdint.h>

#define NN 65536
#define NE 262144

typedef __attribute__((ext_vector_type(8))) short bf16x8;
typedef __attribute__((ext_vector_type(4))) float f32x4;

__device__ __forceinline__ short f2bf(float f) {
  union { float f; uint32_t u; } v; v.f = f;
  uint32_t u = v.u + 0x7fffu + ((v.u >> 16) & 1u);
  return (short)(u >> 16);
}

// w1t[n][k] (n<256, k<32, zero-padded k>=10) = w1[k][n]; w2t[n][k] = w2[k][n]
__global__ __launch_bounds__(256) void prep_weights(
    const float* __restrict__ w1_0, const float* __restrict__ w1_1,
    const float* __restrict__ w2_0, const float* __restrict__ w2_1,
    short* __restrict__ w1t0, short* __restrict__ w1t1,
    short* __restrict__ w2t0, short* __restrict__ w2t1) {
  int t = blockIdx.x * 256 + threadIdx.x;  // grid covers 65536
  if (t < 8192) {
    int n = t >> 5, k = t & 31;
    w1t0[t] = (k < 10) ? f2bf(w1_0[k * 256 + n]) : (short)0;
    w1t1[t] = (k < 10) ? f2bf(w1_1[k * 256 + n]) : (short)0;
  }
  if (t < 32768) {
    int n = t >> 8, k = t & 255;
    w2t1[t] = f2bf(w2_1[k * 128 + n]);
  }
  {
    int n = t >> 8, k = t & 255;
    w2t0[t] = f2bf(w2_0[k * 256 + n]);
  }
}

// eab[e][k] bf16, k<16 zero-padded (real K=10)
__global__ __launch_bounds__(256) void prep_ea(const float* __restrict__ ea,
                                               short* __restrict__ eab) {
  int idx = blockIdx.x * 256 + threadIdx.x;  // grid = E*16/256
  int e = idx >> 4, k = idx & 15;
  eab[idx] = (k < 10) ? f2bf(ea[e * 10 + k]) : (short)0;
}

// Fused per-layer edge kernel: 64 edges/block, 4 waves, 2-phase k-split.
template <int N2, int OUTC, bool DO_CNT>
__global__ __launch_bounds__(256, 3) void edge_kernel(
    const float* __restrict__ x, const int* __restrict__ ei,
    const short* __restrict__ eab, const short* __restrict__ w1t,
    const float* __restrict__ b1, const short* __restrict__ w2t,
    const float* __restrict__ b2, float* __restrict__ ssum,
    float* __restrict__ cnt) {
  constexpr int NT2 = N2 / 64;                  // 4 (layer0) / 2 (layer1)
  constexpr int LOGO = (OUTC == 16) ? 4 : 3;
  constexpr int SLOTS = 4 * (16 / OUTC);        // 4 / 8
  constexpr int PADO = OUTC + 1;                // pad breaks bank aliasing
  constexpr int PART = SLOTS * 64 * PADO * 4;   // 17408 / 18432
  constexpr int HSZ = (PART > 64 * 128 * 2) ? PART : 64 * 128 * 2;
  __shared__ alignas(16) char smem[HSZ + 64 * 20 * 4];
  char* const hB = smem;                        // h tile [64][128] bf16, swizzled
  float* const partial = (float*)smem;          // overlays hB after GEMM2 (barriered)
  float* const xs = (float*)(smem + HSZ);       // x[src] tile [64][20] f32 (pad 20)

  const int tid = threadIdx.x;
  const int wave = tid >> 6;
  const int lane = tid & 63;
  const int g = lane >> 4;   // k-group
  const int lr = lane & 15;  // row(A) / col(B,D)
  const int e0 = blockIdx.x * 64;

  // ---- stage x[src] tile: [64][20] f32 (pad 20 -> conflict-free epilogue reads)
  {
    int e = tid >> 2, q = tid & 3;
    int s = ei[e0 + e];
    float4 v = *(const float4*)(x + (size_t)s * 16 + q * 4);
    *(float4*)(xs + e * 20 + q * 4) = v;
  }

  // ---- A fragments for GEMM1 direct from global bf16 (k>=16 are zero)
  bf16x8 a1[4];
#pragma unroll
  for (int mt = 0; mt < 4; ++mt) {
    int row = mt * 16 + lr;
    if (g < 2)
      a1[mt] = *(const bf16x8*)(eab + (size_t)(e0 + row) * 16 + g * 8);
    else
      a1[mt] = (bf16x8){0, 0, 0, 0, 0, 0, 0, 0};
  }

  f32x4 acc[4][NT2];
#pragma unroll
  for (int mt = 0; mt < 4; ++mt)
#pragma unroll
    for (int nt = 0; nt < NT2; ++nt) acc[mt][nt] = (f32x4){0.f, 0.f, 0.f, 0.f};

#pragma unroll
  for (int p = 0; p < 2; ++p) {
    // ---- GEMM1 phase p: h cols [p*128, p*128+128), wave owns 32 cols ----
    f32x4 acc1[4][2];
#pragma unroll
    for (int mt = 0; mt < 4; ++mt)
#pragma unroll
      for (int n2 = 0; n2 < 2; ++n2) acc1[mt][n2] = (f32x4){0.f, 0.f, 0.f, 0.f};
#pragma unroll
    for (int n2 = 0; n2 < 2; ++n2) {
      int colh = p * 128 + wave * 32 + n2 * 16 + lr;
      bf16x8 b = *(const bf16x8*)(w1t + colh * 32 + g * 8);
#pragma unroll
      for (int mt = 0; mt < 4; ++mt)
        acc1[mt][n2] = __builtin_amdgcn_mfma_f32_16x16x32_bf16(a1[mt], b, acc1[mt][n2], 0, 0, 0);
    }
    // h = relu(+b1) -> hB [64][128] bf16, XOR-swizzled rows
#pragma unroll
    for (int n2 = 0; n2 < 2; ++n2) {
      int colh = p * 128 + wave * 32 + n2 * 16 + lr;
      int c = wave * 32 + n2 * 16 + lr;
      float bb = b1[colh];
#pragma unroll
      for (int mt = 0; mt < 4; ++mt)
#pragma unroll
        for (int r = 0; r < 4; ++r) {
          int row = mt * 16 + g * 4 + r;
          float hv = fmaxf(acc1[mt][n2][r] + bb, 0.0f);
          *(short*)(hB + ((row * 256 + c * 2) ^ ((row & 7) << 4))) = f2bf(hv);
        }
    }
    __syncthreads();
    // ---- GEMM2 phase p: accumulate k-slice [p*128, p*128+128) ----
#pragma unroll
    for (int ks = 0; ks < 4; ++ks) {
      bf16x8 a2[4];
#pragma unroll
      for (int mt = 0; mt < 4; ++mt) {
        int row = mt * 16 + lr;
        a2[mt] = *(const bf16x8*)(hB + ((row * 256 + ks * 64 + g * 16) ^ ((row & 7) << 4)));
      }
#pragma unroll
      for (int nt = 0; nt < NT2; ++nt) {
        int colo = wave * (NT2 * 16) + nt * 16 + lr;
        bf16x8 b = *(const bf16x8*)(w2t + colo * 256 + p * 128 + ks * 32 + g * 8);
#pragma unroll
        for (int mt = 0; mt < 4; ++mt)
          acc[mt][nt] = __builtin_amdgcn_mfma_f32_16x16x32_bf16(a2[mt], b, acc[mt][nt], 0, 0, 0);
      }
    }
    __syncthreads();  // GEMM2 reads done -> next phase may overwrite hB / epilogue may overlay
  }

  // ---- epilogue: msg partials in registers; one f32 LDS write per (e,o) slot ----
  const int o = lr & (OUTC - 1);
  const int slot = wave * (16 / OUTC) + (lr >> LOGO);
  float b2c[NT2];
  int iv[NT2];
#pragma unroll
  for (int nt = 0; nt < NT2; ++nt) {
    int colo = wave * (NT2 * 16) + nt * 16 + lr;
    b2c[nt] = b2[colo];
    iv[nt] = colo >> LOGO;
  }
#pragma unroll
  for (int mt = 0; mt < 4; ++mt)
#pragma unroll
    for (int r = 0; r < 4; ++r) {
      int e = mt * 16 + g * 4 + r;
      float m = 0.f;
#pragma unroll
      for (int nt = 0; nt < NT2; ++nt)
        m += (acc[mt][nt][r] + b2c[nt]) * xs[e * 20 + iv[nt]];
      partial[(slot * 64 + e) * PADO + o] = m;
    }
  __syncthreads();

  // ---- cross-slot reduce + atomic scatter ----
  constexpr int REP = 64 * OUTC / 256;  // 4 / 2
  {
    int e = tid >> 2;
    int d = ei[NE + e0 + e];
#pragma unroll
    for (int j = 0; j < REP; ++j) {
      int pr = tid * REP + j;
      int oo = pr & (OUTC - 1);
      float s = 0.f;
#pragma unroll
      for (int sl = 0; sl < SLOTS; ++sl) s += partial[(sl * 64 + e) * PADO + oo];
      atomicAdd(&ssum[(size_t)d * OUTC + oo], s);
    }
  }
  if (DO_CNT && tid < 64) atomicAdd(&cnt[ei[NE + e0 + tid]], 1.0f);
}

// x_out = relu(ssum/max(cnt,1) + x_in @ root + bias), one thread per node
template <int OUTC>
__global__ __launch_bounds__(256) void node_kernel(
    const float* __restrict__ xin, const float* __restrict__ ssum,
    const float* __restrict__ cnt, const float* __restrict__ root,
    const float* __restrict__ bias, float* __restrict__ xout) {
  int n = blockIdx.x * 256 + threadIdx.x;
  float inv = 1.0f / fmaxf(cnt[n], 1.0f);
  float xi[16];
#pragma unroll
  for (int i = 0; i < 4; ++i) {
    float4 v = ((const float4*)(xin + (size_t)n * 16))[i];
    xi[4 * i] = v.x; xi[4 * i + 1] = v.y; xi[4 * i + 2] = v.z; xi[4 * i + 3] = v.w;
  }
#pragma unroll
  for (int o = 0; o < OUTC; ++o) {
    float a = ssum[(size_t)n * OUTC + o] * inv + bias[o];
#pragma unroll
    for (int i = 0; i < 16; ++i) a += xi[i] * root[i * OUTC + o];
    xout[(size_t)n * OUTC + o] = fmaxf(a, 0.f);
  }
}

__global__ __launch_bounds__(256) void final_kernel(
    const float* __restrict__ x2, const int* __restrict__ ei,
    const float* __restrict__ fcw, const float* __restrict__ fcb,
    float* __restrict__ out) {
  int e = blockIdx.x * 256 + threadIdx.x;
  int s = ei[e], d = ei[NE + e];
  float acc = fcb[0];
  const float* xsr = x2 + (size_t)s * 8;
  const float* xdr = x2 + (size_t)d * 8;
#pragma unroll
  for (int c = 0; c < 8; ++c) acc += xsr[c] * fcw[c];
#pragma unroll
  for (int c = 0; c < 8; ++c) acc += xdr[c] * fcw[8 + c];
  out[e] = 1.0f / (1.0f + __expf(-acc));
}

extern "C" void kernel_launch(void* const* d_in, const int* in_sizes, int n_in,
                              void* d_out, int out_size, void* d_ws, size_t ws_size,
                              hipStream_t stream) {
  const float* x      = (const float*)d_in[0];
  const int*   ei     = (const int*)d_in[1];
  const float* ea     = (const float*)d_in[2];
  const float* w1_0   = (const float*)d_in[3];
  const float* b1_0   = (const float*)d_in[4];
  const float* w2_0   = (const float*)d_in[5];
  const float* b2_0   = (const float*)d_in[6];
  const float* root_0 = (const float*)d_in[7];
  const float* bias_0 = (const float*)d_in[8];
  const float* w1_1   = (const float*)d_in[9];
  const float* b1_1   = (const float*)d_in[10];
  const float* w2_1   = (const float*)d_in[11];
  const float* b2_1   = (const float*)d_in[12];
  const float* root_1 = (const float*)d_in[13];
  const float* bias_1 = (const float*)d_in[14];
  const float* fc_w   = (const float*)d_in[15];
  const float* fc_b   = (const float*)d_in[16];
  float* out = (float*)d_out;

  char* ws = (char*)d_ws;
  float* ssum0 = (float*)(ws);                         // 4 MB
  float* x1    = (float*)(ws + (4u << 20));            // 4 MB
  float* ssum1 = (float*)(ws + (8u << 20));            // 2 MB
  float* x2    = (float*)(ws + (10u << 20));           // 2 MB
  float* cnt   = (float*)(ws + (12u << 20));           // 256 KB
  short* w1t0  = (short*)(ws + (12u << 20) + (256u << 10));
  short* w1t1  = w1t0 + 8192;
  short* w2t0  = w1t1 + 8192;
  short* w2t1  = w2t0 + 65536;
  short* eab   = w2t1 + 32768;                         // 8 MB

  hipMemsetAsync(ssum0, 0, (size_t)NN * 16 * 4, stream);
  hipMemsetAsync(ssum1, 0, (size_t)NN * 8 * 4, stream);
  hipMemsetAsync(cnt, 0, (size_t)NN * 4, stream);
  prep_weights<<<256, 256, 0, stream>>>(w1_0, w1_1, w2_0, w2_1, w1t0, w1t1, w2t0, w2t1);
  prep_ea<<<NE * 16 / 256, 256, 0, stream>>>(ea, eab);

  edge_kernel<256, 16, true><<<NE / 64, 256, 0, stream>>>(
      x, ei, eab, w1t0, b1_0, w2t0, b2_0, ssum0, cnt);
  node_kernel<16><<<NN / 256, 256, 0, stream>>>(x, ssum0, cnt, root_0, bias_0, x1);
  edge_kernel<128, 8, false><<<NE / 64, 256, 0, stream>>>(
      x1, ei, eab, w1t1, b1_1, w2t1, b2_1, ssum1, nullptr);
  node_kernel<8><<<NN / 256, 256, 0, stream>>>(x1, ssum1, cnt, root_1, bias_1, x2);
  final_kernel<<<NE / 256, 256, 0, stream>>>(x2, ei, fc_w, fc_b, out);
}

// Round 3
// 221.897 us; speedup vs baseline: 1.3074x; 1.3074x over previous
//
#include <hip/hip_runtime.h>
#include <stdint.h>

#define NN 65536
#define NE 262144

typedef __attribute__((ext_vector_type(8))) short bf16x8;
typedef __attribute__((ext_vector_type(4))) float f32x4;

__device__ __forceinline__ short f2bf(float f) {
  union { float f; uint32_t u; } v; v.f = f;
  uint32_t u = v.u + 0x7fffu + ((v.u >> 16) & 1u);
  return (short)(u >> 16);
}

// Merged prep: eab[e][k] bf16 (k<16, zero-padded from 10) + transposed bf16 weights
// w1t[n][k] (k<32 zero-padded) = w1[k][n]; w2t[n][k] = w2[k][n]
__global__ __launch_bounds__(256) void prep_all(
    const float* __restrict__ ea, short* __restrict__ eab,
    const float* __restrict__ w1_0, const float* __restrict__ w1_1,
    const float* __restrict__ w2_0, const float* __restrict__ w2_1,
    short* __restrict__ w1t0, short* __restrict__ w1t1,
    short* __restrict__ w2t0, short* __restrict__ w2t1) {
  int idx = blockIdx.x * 256 + threadIdx.x;  // grid = NE*16/256
  {
    int e = idx >> 4, k = idx & 15;
    eab[idx] = (k < 10) ? f2bf(ea[e * 10 + k]) : (short)0;
  }
  if (idx < 65536) {
    if (idx < 8192) {
      int n = idx >> 5, k = idx & 31;
      w1t0[idx] = (k < 10) ? f2bf(w1_0[k * 256 + n]) : (short)0;
      w1t1[idx] = (k < 10) ? f2bf(w1_1[k * 256 + n]) : (short)0;
    }
    if (idx < 32768) {
      int n = idx >> 8, k = idx & 255;
      w2t1[idx] = f2bf(w2_1[k * 128 + n]);
    }
    {
      int n = idx >> 8, k = idx & 255;
      w2t0[idx] = f2bf(w2_0[k * 256 + n]);
    }
  }
}

// Fused per-layer edge kernel: 64 edges/block, 4 waves, SEQUENTIAL GEMM1->GEMM2
// (acc1 dies before acc lives: keeps peak VGPR ~90, no spill).
template <int N2, int OUTC, bool DO_CNT>
__global__ __launch_bounds__(256) void edge_kernel(
    const float* __restrict__ x, const int* __restrict__ ei,
    const short* __restrict__ eab, const short* __restrict__ w1t,
    const float* __restrict__ b1, const short* __restrict__ w2t,
    const float* __restrict__ b2, float* __restrict__ ssum,
    float* __restrict__ cnt) {
  constexpr int NT2 = N2 / 64;                 // 4 (layer0) / 2 (layer1)
  constexpr int LOGO = (OUTC == 16) ? 4 : 3;
  constexpr int SLOTS = 4 * (16 / OUTC);       // 4 / 8
  constexpr int PADO = OUTC + 1;
  __shared__ alignas(16) char smem[64 * 256 * 2 + 64 * 20 * 4];  // 37.9 KB
  char* const hB = smem;                       // h [64][256] bf16, XOR-swizzled
  float* const partial = (float*)smem;         // overlays hB after GEMM2 (barriered)
  float* const xs = (float*)(smem + 64 * 256 * 2);  // x[src] [64][20] f32

  const int tid = threadIdx.x;
  const int wave = tid >> 6;
  const int lane = tid & 63;
  const int g = lane >> 4;   // k-group
  const int lr = lane & 15;  // row(A) / col(B,D)
  const int e0 = blockIdx.x * 64;

  // ---- stage x[src] tile [64][20] f32 (pad 20 -> conflict-free epilogue reads)
  {
    int e = tid >> 2, q = tid & 3;
    int s = ei[e0 + e];
    float4 v = *(const float4*)(x + (size_t)s * 16 + q * 4);
    *(float4*)(xs + e * 20 + q * 4) = v;
  }

  // ---- A fragments for GEMM1 direct from global bf16 (k>=16 are zero)
  bf16x8 a1[4];
#pragma unroll
  for (int mt = 0; mt < 4; ++mt) {
    int row = mt * 16 + lr;
    if (g < 2)
      a1[mt] = *(const bf16x8*)(eab + (size_t)(e0 + row) * 16 + g * 8);
    else
      a1[mt] = (bf16x8){0, 0, 0, 0, 0, 0, 0, 0};
  }

  // ---- GEMM1 full width: hpre[64][256], wave owns cols [wave*64, +64) ----
  {
    f32x4 acc1[4][4];
#pragma unroll
    for (int mt = 0; mt < 4; ++mt)
#pragma unroll
      for (int nt = 0; nt < 4; ++nt) acc1[mt][nt] = (f32x4){0.f, 0.f, 0.f, 0.f};
#pragma unroll
    for (int nt = 0; nt < 4; ++nt) {
      int col = wave * 64 + nt * 16 + lr;
      bf16x8 b = *(const bf16x8*)(w1t + col * 32 + g * 8);
#pragma unroll
      for (int mt = 0; mt < 4; ++mt)
        acc1[mt][nt] = __builtin_amdgcn_mfma_f32_16x16x32_bf16(a1[mt], b, acc1[mt][nt], 0, 0, 0);
    }
    // h = relu(+b1) -> hB [64][256] bf16, XOR-swizzled rows (stride 512B)
#pragma unroll
    for (int nt = 0; nt < 4; ++nt) {
      int col = wave * 64 + nt * 16 + lr;
      float bb = b1[col];
#pragma unroll
      for (int mt = 0; mt < 4; ++mt)
#pragma unroll
        for (int r = 0; r < 4; ++r) {
          int row = mt * 16 + g * 4 + r;
          float hv = fmaxf(acc1[mt][nt][r] + bb, 0.0f);
          *(short*)(hB + ((row * 512 + col * 2) ^ ((row & 7) << 4))) = f2bf(hv);
        }
    }
  }
  __syncthreads();

  // ---- GEMM2: msg_pre[64][N2] = h @ w2t^T, B-frags direct from global ----
  f32x4 acc[4][NT2];
#pragma unroll
  for (int mt = 0; mt < 4; ++mt)
#pragma unroll
    for (int nt = 0; nt < NT2; ++nt) acc[mt][nt] = (f32x4){0.f, 0.f, 0.f, 0.f};
#pragma unroll
  for (int ks = 0; ks < 8; ++ks) {
    bf16x8 a2[4];
#pragma unroll
    for (int mt = 0; mt < 4; ++mt) {
      int row = mt * 16 + lr;
      a2[mt] = *(const bf16x8*)(hB + ((row * 512 + ks * 64 + g * 16) ^ ((row & 7) << 4)));
    }
#pragma unroll
    for (int nt = 0; nt < NT2; ++nt) {
      int colo = wave * (NT2 * 16) + nt * 16 + lr;
      bf16x8 b = *(const bf16x8*)(w2t + colo * 256 + ks * 32 + g * 8);
#pragma unroll
      for (int mt = 0; mt < 4; ++mt)
        acc[mt][nt] = __builtin_amdgcn_mfma_f32_16x16x32_bf16(a2[mt], b, acc[mt][nt], 0, 0, 0);
    }
  }
  __syncthreads();  // GEMM2 reads done -> safe to overlay partial onto hB

  // ---- epilogue: msg partials in registers; one f32 LDS write per (e,o,slot) ----
  const int o = lr & (OUTC - 1);
  const int slot = wave * (16 / OUTC) + (lr >> LOGO);
  float b2c[NT2];
  int iv[NT2];
#pragma unroll
  for (int nt = 0; nt < NT2; ++nt) {
    int colo = wave * (NT2 * 16) + nt * 16 + lr;
    b2c[nt] = b2[colo];
    iv[nt] = colo >> LOGO;
  }
#pragma unroll
  for (int mt = 0; mt < 4; ++mt)
#pragma unroll
    for (int r = 0; r < 4; ++r) {
      int e = mt * 16 + g * 4 + r;
      float m = 0.f;
#pragma unroll
      for (int nt = 0; nt < NT2; ++nt)
        m += (acc[mt][nt][r] + b2c[nt]) * xs[e * 20 + iv[nt]];
      partial[(slot * 64 + e) * PADO + o] = m;
    }
  __syncthreads();

  // ---- cross-slot reduce + atomic scatter ----
  constexpr int REP = 64 * OUTC / 256;  // 4 / 2
  {
    int e = tid >> 2;
    int d = ei[NE + e0 + e];
#pragma unroll
    for (int j = 0; j < REP; ++j) {
      int pr = tid * REP + j;
      int oo = pr & (OUTC - 1);
      float s = 0.f;
#pragma unroll
      for (int sl = 0; sl < SLOTS; ++sl) s += partial[(sl * 64 + e) * PADO + oo];
      atomicAdd(&ssum[(size_t)d * OUTC + oo], s);
    }
  }
  if (DO_CNT && tid < 64) atomicAdd(&cnt[ei[NE + e0 + tid]], 1.0f);
}

// x_out = relu(ssum/max(cnt,1) + x_in @ root + bias), one thread per node
template <int OUTC>
__global__ __launch_bounds__(256) void node_kernel(
    const float* __restrict__ xin, const float* __restrict__ ssum,
    const float* __restrict__ cnt, const float* __restrict__ root,
    const float* __restrict__ bias, float* __restrict__ xout) {
  int n = blockIdx.x * 256 + threadIdx.x;
  float inv = 1.0f / fmaxf(cnt[n], 1.0f);
  float xi[16];
#pragma unroll
  for (int i = 0; i < 4; ++i) {
    float4 v = ((const float4*)(xin + (size_t)n * 16))[i];
    xi[4 * i] = v.x; xi[4 * i + 1] = v.y; xi[4 * i + 2] = v.z; xi[4 * i + 3] = v.w;
  }
#pragma unroll
  for (int o = 0; o < OUTC; ++o) {
    float a = ssum[(size_t)n * OUTC + o] * inv + bias[o];
#pragma unroll
    for (int i = 0; i < 16; ++i) a += xi[i] * root[i * OUTC + o];
    xout[(size_t)n * OUTC + o] = fmaxf(a, 0.f);
  }
}

__global__ __launch_bounds__(256) void final_kernel(
    const float* __restrict__ x2, const int* __restrict__ ei,
    const float* __restrict__ fcw, const float* __restrict__ fcb,
    float* __restrict__ out) {
  int e = blockIdx.x * 256 + threadIdx.x;
  int s = ei[e], d = ei[NE + e];
  float acc = fcb[0];
  const float* xsr = x2 + (size_t)s * 8;
  const float* xdr = x2 + (size_t)d * 8;
#pragma unroll
  for (int c = 0; c < 8; ++c) acc += xsr[c] * fcw[c];
#pragma unroll
  for (int c = 0; c < 8; ++c) acc += xdr[c] * fcw[8 + c];
  out[e] = 1.0f / (1.0f + __expf(-acc));
}

extern "C" void kernel_launch(void* const* d_in, const int* in_sizes, int n_in,
                              void* d_out, int out_size, void* d_ws, size_t ws_size,
                              hipStream_t stream) {
  const float* x      = (const float*)d_in[0];
  const int*   ei     = (const int*)d_in[1];
  const float* ea     = (const float*)d_in[2];
  const float* w1_0   = (const float*)d_in[3];
  const float* b1_0   = (const float*)d_in[4];
  const float* w2_0   = (const float*)d_in[5];
  const float* b2_0   = (const float*)d_in[6];
  const float* root_0 = (const float*)d_in[7];
  const float* bias_0 = (const float*)d_in[8];
  const float* w1_1   = (const float*)d_in[9];
  const float* b1_1   = (const float*)d_in[10];
  const float* w2_1   = (const float*)d_in[11];
  const float* b2_1   = (const float*)d_in[12];
  const float* root_1 = (const float*)d_in[13];
  const float* bias_1 = (const float*)d_in[14];
  const float* fc_w   = (const float*)d_in[15];
  const float* fc_b   = (const float*)d_in[16];
  float* out = (float*)d_out;

  char* ws = (char*)d_ws;
  float* ssum0 = (float*)(ws);                         // 4 MB
  float* x1    = (float*)(ws + (4u << 20));            // 4 MB
  float* ssum1 = (float*)(ws + (8u << 20));            // 2 MB
  float* x2    = (float*)(ws + (10u << 20));           // 2 MB
  float* cnt   = (float*)(ws + (12u << 20));           // 256 KB
  short* w1t0  = (short*)(ws + (12u << 20) + (256u << 10));
  short* w1t1  = w1t0 + 8192;
  short* w2t0  = w1t1 + 8192;
  short* w2t1  = w2t0 + 65536;
  short* eab   = w2t1 + 32768;                         // 8 MB

  hipMemsetAsync(ssum0, 0, (size_t)NN * 16 * 4, stream);
  hipMemsetAsync(ssum1, 0, (size_t)NN * 8 * 4, stream);
  hipMemsetAsync(cnt, 0, (size_t)NN * 4, stream);
  prep_all<<<NE * 16 / 256, 256, 0, stream>>>(ea, eab, w1_0, w1_1, w2_0, w2_1,
                                              w1t0, w1t1, w2t0, w2t1);

  edge_kernel<256, 16, true><<<NE / 64, 256, 0, stream>>>(
      x, ei, eab, w1t0, b1_0, w2t0, b2_0, ssum0, cnt);
  node_kernel<16><<<NN / 256, 256, 0, stream>>>(x, ssum0, cnt, root_0, bias_0, x1);
  edge_kernel<128, 8, false><<<NE / 64, 256, 0, stream>>>(
      x1, ei, eab, w1t1, b1_1, w2t1, b2_1, ssum1, nullptr);
  node_kernel<8><<<NN / 256, 256, 0, stream>>>(x1, ssum1, cnt, root_1, bias_1, x2);
  final_kernel<<<NE / 256, 256, 0, stream>>>(x2, ei, fc_w, fc_b, out);
}

// Round 4
// 190.373 us; speedup vs baseline: 1.5239x; 1.1656x over previous
//
#include <hip/hip_runtime.h>
#include <stdint.h>

#define NN 65536
#define NE 262144

typedef __attribute__((ext_vector_type(8))) short bf16x8;
typedef __attribute__((ext_vector_type(4))) float f32x4;

__device__ __forceinline__ short f2bf(float f) {
  union { float f; uint32_t u; } v; v.f = f;
  uint32_t u = v.u + 0x7fffu + ((v.u >> 16) & 1u);
  return (short)(u >> 16);
}
__device__ __forceinline__ uint32_t pack2(float a, float b) {
  return (uint32_t)(uint16_t)f2bf(a) | ((uint32_t)(uint16_t)f2bf(b) << 16);
}

// Merged prep: eab[e][k] bf16 (k<16, zero-padded from 10) + transposed bf16 weights
// w1t[n][k] (k<32 zero-padded) = w1[k][n]; w2t[n][k] = w2[k][n]
__global__ __launch_bounds__(256) void prep_all(
    const float* __restrict__ ea, short* __restrict__ eab,
    const float* __restrict__ w1_0, const float* __restrict__ w1_1,
    const float* __restrict__ w2_0, const float* __restrict__ w2_1,
    short* __restrict__ w1t0, short* __restrict__ w1t1,
    short* __restrict__ w2t0, short* __restrict__ w2t1) {
  int idx = blockIdx.x * 256 + threadIdx.x;  // grid = NE*16/256
  {
    int e = idx >> 4, k = idx & 15;
    eab[idx] = (k < 10) ? f2bf(ea[e * 10 + k]) : (short)0;
  }
  if (idx < 65536) {
    if (idx < 8192) {
      int n = idx >> 5, k = idx & 31;
      w1t0[idx] = (k < 10) ? f2bf(w1_0[k * 256 + n]) : (short)0;
      w1t1[idx] = (k < 10) ? f2bf(w1_1[k * 256 + n]) : (short)0;
    }
    if (idx < 32768) {
      int n = idx >> 8, k = idx & 255;
      w2t1[idx] = f2bf(w2_1[k * 128 + n]);
    }
    {
      int n = idx >> 8, k = idx & 255;
      w2t0[idx] = f2bf(w2_0[k * 256 + n]);
    }
  }
}

// Fused per-layer edge kernel: 64 edges/block, 4 waves.
// GEMM1 computed SWAPPED (A=w1^T, B=ea^T) so each thread holds 4 consecutive
// h-k values for one edge -> packed ds_write_b64 h-stores.
// GEMM2 B-frags (w2t, global/L2) are software-pipelined (prefetch depth 1,
// ks=0 frags issued before GEMM1 so their latency hides under it).
template <int N2, int OUTC, bool DO_CNT>
__global__ __launch_bounds__(256) void edge_kernel(
    const float* __restrict__ x, const int* __restrict__ ei,
    const short* __restrict__ eab, const short* __restrict__ w1t,
    const float* __restrict__ b1, const short* __restrict__ w2t,
    const float* __restrict__ b2, float* __restrict__ ssum,
    float* __restrict__ cnt) {
  constexpr int NT2 = N2 / 64;                 // 4 (layer0) / 2 (layer1)
  constexpr int LOGO = (OUTC == 16) ? 4 : 3;
  constexpr int SLOTS = 4 * (16 / OUTC);       // 4 / 8
  constexpr int PADO = OUTC + 1;
  __shared__ alignas(16) char smem[64 * 256 * 2 + 64 * 20 * 4];  // 37.9 KB
  char* const hB = smem;                       // h [64 edges][256 k] bf16, XOR-swz
  float* const partial = (float*)smem;         // overlays hB after GEMM2 (barriered)
  float* const xs = (float*)(smem + 64 * 256 * 2);  // x[src] [64][20] f32

  const int tid = threadIdx.x;
  const int wave = tid >> 6;
  const int lane = tid & 63;
  const int g = lane >> 4;   // k-group
  const int lr = lane & 15;  // row/col within 16x16 tile
  const int e0 = blockIdx.x * 64;

  // ---- GEMM1 operand frags (needed first) ----
  bf16x8 aw[4];  // A = w1^T rows n = (wave*4+ml)*16 + lr, k contiguous
#pragma unroll
  for (int ml = 0; ml < 4; ++ml)
    aw[ml] = *(const bf16x8*)(w1t + ((wave * 4 + ml) * 16 + lr) * 32 + g * 8);
  bf16x8 be[4];  // B = ea^T cols e = et*16 + lr, k contiguous (k>=16 zero)
#pragma unroll
  for (int et = 0; et < 4; ++et) {
    if (g < 2)
      be[et] = *(const bf16x8*)(eab + (size_t)(e0 + et * 16 + lr) * 16 + g * 8);
    else
      be[et] = (bf16x8){0, 0, 0, 0, 0, 0, 0, 0};
  }

  // ---- GEMM2 B-frags for ks=0: issue now, latency hides under GEMM1 ----
  bf16x8 bcur[NT2];
#pragma unroll
  for (int nt = 0; nt < NT2; ++nt) {
    int colo = wave * (NT2 * 16) + nt * 16 + lr;
    bcur[nt] = *(const bf16x8*)(w2t + colo * 256 + g * 8);
  }

  // ---- stage x[src] tile [64][20] f32 ----
  {
    int e = tid >> 2, q = tid & 3;
    int s = ei[e0 + e];
    float4 v = *(const float4*)(x + (size_t)s * 16 + q * 4);
    *(float4*)(xs + e * 20 + q * 4) = v;
  }

  // ---- GEMM1 (swapped): acc1[ml][et] holds h[k=(wave*4+ml)*16+g*4+r][e=et*16+lr]
  {
    f32x4 acc1[4][4];
#pragma unroll
    for (int ml = 0; ml < 4; ++ml)
#pragma unroll
      for (int et = 0; et < 4; ++et) acc1[ml][et] = (f32x4){0.f, 0.f, 0.f, 0.f};
#pragma unroll
    for (int et = 0; et < 4; ++et)
#pragma unroll
      for (int ml = 0; ml < 4; ++ml)
        acc1[ml][et] = __builtin_amdgcn_mfma_f32_16x16x32_bf16(aw[ml], be[et], acc1[ml][et], 0, 0, 0);
    // h = relu(+b1) -> hB, packed 4-k ds_write_b64 per (ml,et)
#pragma unroll
    for (int ml = 0; ml < 4; ++ml) {
      int kb = (wave * 4 + ml) * 16 + g * 4;
      float4 bb = *(const float4*)(b1 + kb);
#pragma unroll
      for (int et = 0; et < 4; ++et) {
        int e = et * 16 + lr;
        float v0 = fmaxf(acc1[ml][et][0] + bb.x, 0.f);
        float v1 = fmaxf(acc1[ml][et][1] + bb.y, 0.f);
        float v2 = fmaxf(acc1[ml][et][2] + bb.z, 0.f);
        float v3 = fmaxf(acc1[ml][et][3] + bb.w, 0.f);
        int2 w; w.x = (int)pack2(v0, v1); w.y = (int)pack2(v2, v3);
        *(int2*)(hB + ((e * 512 + kb * 2) ^ ((e & 7) << 4))) = w;
      }
    }
  }
  __syncthreads();

  // ---- GEMM2: msg_pre[64][N2] = h @ w2, B prefetch depth 1 ----
  f32x4 acc[4][NT2];
#pragma unroll
  for (int mt = 0; mt < 4; ++mt)
#pragma unroll
    for (int nt = 0; nt < NT2; ++nt) acc[mt][nt] = (f32x4){0.f, 0.f, 0.f, 0.f};
#pragma unroll
  for (int ks = 0; ks < 8; ++ks) {
    bf16x8 bnxt[NT2];
    if (ks < 7) {
#pragma unroll
      for (int nt = 0; nt < NT2; ++nt) {
        int colo = wave * (NT2 * 16) + nt * 16 + lr;
        bnxt[nt] = *(const bf16x8*)(w2t + colo * 256 + (ks + 1) * 32 + g * 8);
      }
    }
    bf16x8 a2[4];
#pragma unroll
    for (int mt = 0; mt < 4; ++mt) {
      int e = mt * 16 + lr;
      a2[mt] = *(const bf16x8*)(hB + ((e * 512 + ks * 64 + g * 16) ^ ((e & 7) << 4)));
    }
#pragma unroll
    for (int nt = 0; nt < NT2; ++nt)
#pragma unroll
      for (int mt = 0; mt < 4; ++mt)
        acc[mt][nt] = __builtin_amdgcn_mfma_f32_16x16x32_bf16(a2[mt], bcur[nt], acc[mt][nt], 0, 0, 0);
    if (ks < 7) {
#pragma unroll
      for (int nt = 0; nt < NT2; ++nt) bcur[nt] = bnxt[nt];
    }
  }
  __syncthreads();  // GEMM2 reads done -> safe to overlay partial onto hB

  // ---- epilogue: msg partials in registers; one f32 LDS write per (e,o,slot) ----
  const int o = lr & (OUTC - 1);
  const int slot = wave * (16 / OUTC) + (lr >> LOGO);
  float b2c[NT2];
  int iv[NT2];
#pragma unroll
  for (int nt = 0; nt < NT2; ++nt) {
    int colo = wave * (NT2 * 16) + nt * 16 + lr;
    b2c[nt] = b2[colo];
    iv[nt] = colo >> LOGO;
  }
#pragma unroll
  for (int mt = 0; mt < 4; ++mt)
#pragma unroll
    for (int r = 0; r < 4; ++r) {
      int e = mt * 16 + g * 4 + r;
      float m = 0.f;
#pragma unroll
      for (int nt = 0; nt < NT2; ++nt)
        m += (acc[mt][nt][r] + b2c[nt]) * xs[e * 20 + iv[nt]];
      partial[(slot * 64 + e) * PADO + o] = m;
    }
  __syncthreads();

  // ---- cross-slot reduce + atomic scatter ----
  constexpr int REP = 64 * OUTC / 256;  // 4 / 2
  {
    int e = tid >> 2;
    int d = ei[NE + e0 + e];
#pragma unroll
    for (int j = 0; j < REP; ++j) {
      int pr = tid * REP + j;
      int oo = pr & (OUTC - 1);
      float s = 0.f;
#pragma unroll
      for (int sl = 0; sl < SLOTS; ++sl) s += partial[(sl * 64 + e) * PADO + oo];
      atomicAdd(&ssum[(size_t)d * OUTC + oo], s);
    }
  }
  if (DO_CNT && tid < 64) atomicAdd(&cnt[ei[NE + e0 + tid]], 1.0f);
}

// x_out = relu(ssum/max(cnt,1) + x_in @ root + bias), one thread per node
template <int OUTC>
__global__ __launch_bounds__(256) void node_kernel(
    const float* __restrict__ xin, const float* __restrict__ ssum,
    const float* __restrict__ cnt, const float* __restrict__ root,
    const float* __restrict__ bias, float* __restrict__ xout) {
  int n = blockIdx.x * 256 + threadIdx.x;
  float inv = 1.0f / fmaxf(cnt[n], 1.0f);
  float xi[16];
#pragma unroll
  for (int i = 0; i < 4; ++i) {
    float4 v = ((const float4*)(xin + (size_t)n * 16))[i];
    xi[4 * i] = v.x; xi[4 * i + 1] = v.y; xi[4 * i + 2] = v.z; xi[4 * i + 3] = v.w;
  }
#pragma unroll
  for (int o = 0; o < OUTC; ++o) {
    float a = ssum[(size_t)n * OUTC + o] * inv + bias[o];
#pragma unroll
    for (int i = 0; i < 16; ++i) a += xi[i] * root[i * OUTC + o];
    xout[(size_t)n * OUTC + o] = fmaxf(a, 0.f);
  }
}

__global__ __launch_bounds__(256) void final_kernel(
    const float* __restrict__ x2, const int* __restrict__ ei,
    const float* __restrict__ fcw, const float* __restrict__ fcb,
    float* __restrict__ out) {
  int e = blockIdx.x * 256 + threadIdx.x;
  int s = ei[e], d = ei[NE + e];
  float acc = fcb[0];
  const float* xsr = x2 + (size_t)s * 8;
  const float* xdr = x2 + (size_t)d * 8;
#pragma unroll
  for (int c = 0; c < 8; ++c) acc += xsr[c] * fcw[c];
#pragma unroll
  for (int c = 0; c < 8; ++c) acc += xdr[c] * fcw[8 + c];
  out[e] = 1.0f / (1.0f + __expf(-acc));
}

extern "C" void kernel_launch(void* const* d_in, const int* in_sizes, int n_in,
                              void* d_out, int out_size, void* d_ws, size_t ws_size,
                              hipStream_t stream) {
  const float* x      = (const float*)d_in[0];
  const int*   ei     = (const int*)d_in[1];
  const float* ea     = (const float*)d_in[2];
  const float* w1_0   = (const float*)d_in[3];
  const float* b1_0   = (const float*)d_in[4];
  const float* w2_0   = (const float*)d_in[5];
  const float* b2_0   = (const float*)d_in[6];
  const float* root_0 = (const float*)d_in[7];
  const float* bias_0 = (const float*)d_in[8];
  const float* w1_1   = (const float*)d_in[9];
  const float* b1_1   = (const float*)d_in[10];
  const float* w2_1   = (const float*)d_in[11];
  const float* b2_1   = (const float*)d_in[12];
  const float* root_1 = (const float*)d_in[13];
  const float* bias_1 = (const float*)d_in[14];
  const float* fc_w   = (const float*)d_in[15];
  const float* fc_b   = (const float*)d_in[16];
  float* out = (float*)d_out;

  char* ws = (char*)d_ws;
  float* ssum0 = (float*)(ws);                         // 4 MB
  float* x1    = (float*)(ws + (4u << 20));            // 4 MB
  float* ssum1 = (float*)(ws + (8u << 20));            // 2 MB
  float* x2    = (float*)(ws + (10u << 20));           // 2 MB
  float* cnt   = (float*)(ws + (12u << 20));           // 256 KB
  short* w1t0  = (short*)(ws + (12u << 20) + (256u << 10));
  short* w1t1  = w1t0 + 8192;
  short* w2t0  = w1t1 + 8192;
  short* w2t1  = w2t0 + 65536;
  short* eab   = w2t1 + 32768;                         // 8 MB

  hipMemsetAsync(ssum0, 0, (size_t)NN * 16 * 4, stream);
  hipMemsetAsync(ssum1, 0, (size_t)NN * 8 * 4, stream);
  hipMemsetAsync(cnt, 0, (size_t)NN * 4, stream);
  prep_all<<<NE * 16 / 256, 256, 0, stream>>>(ea, eab, w1_0, w1_1, w2_0, w2_1,
                                              w1t0, w1t1, w2t0, w2t1);

  edge_kernel<256, 16, true><<<NE / 64, 256, 0, stream>>>(
      x, ei, eab, w1t0, b1_0, w2t0, b2_0, ssum0, cnt);
  node_kernel<16><<<NN / 256, 256, 0, stream>>>(x, ssum0, cnt, root_0, bias_0, x1);
  edge_kernel<128, 8, false><<<NE / 64, 256, 0, stream>>>(
      x1, ei, eab, w1t1, b1_1, w2t1, b2_1, ssum1, nullptr);
  node_kernel<8><<<NN / 256, 256, 0, stream>>>(x1, ssum1, cnt, root_1, bias_1, x2);
  final_kernel<<<NE / 256, 256, 0, stream>>>(x2, ei, fc_w, fc_b, out);
}